// Round 10
// baseline (1008.920 us; speedup 1.0000x reference)
//
#include <hip/hip_runtime.h>
#include <hip/hip_bf16.h>

#define C_   256
#define P_   1024
#define N_   32768
#define K_   8192
#define QOFF 8388608   // float offset of indices in d_out
#define CAPL 46        // per-chunk LDS candidate cap
#define GCAP 94        // global per-row cap (2*CAPL <= GCAP, no legit overflow)
#define EPS  8e-4f
#define PANEL   16
#define NPANELW 64     // panels per wave (1024 k / 16)

// scratch in d_out (byte offsets). Quantized region holds xbf/cbbf/cand/cnt/cbsq;
// xsq lives in the INDEX region (read by rescore, then overwritten by index).
// INVARIANT: quantized region untouched until gather (separate, last kernel).
#define XBF_OFF   0u          // ushort[32768*256]  16MB  bf16(x) [n][c]
#define CBBF_OFF  16777216u   // ushort[8192*256]    4MB  bf16(cb) [k][c]
#define CAND_OFF  20971520u   // int[32768*94]   12.3MB  candidate lists
#define CNT_OFF   33292288u   // int[32768]
#define CBSQ_OFF  33423360u   // float[8192]  (ends 33,456,128 < 33,554,432)

typedef __attribute__((ext_vector_type(8))) short bf16x8;
typedef __attribute__((ext_vector_type(4))) float f32x4;

__device__ inline void gload_lds16(const void* g, void* l) {
    __builtin_amdgcn_global_load_lds((const __attribute__((address_space(1))) void*)g,
                                     (__attribute__((address_space(3))) void*)l, 16, 0, 0);
}
__device__ inline unsigned short bfbits(float f) {
    __hip_bfloat16 h = __float2bfloat16(f);
    return *(unsigned short*)&h;
}
__device__ inline unsigned fkey(float f) {
    unsigned u = __float_as_uint(f);
    return (u & 0x80000000u) ? ~u : (u | 0x80000000u);
}
__device__ inline float funkey(unsigned k) {
    unsigned u = (k & 0x80000000u) ? (k ^ 0x80000000u) : ~k;
    return __uint_as_float(u);
}

// ---------- prep_x: transpose x -> bf16 [n][c]; xsq -> index region; cnt=0 ----------
__global__ __launch_bounds__(256) void prep_x(const float* __restrict__ x,
                                              float* __restrict__ outf,
                                              char* __restrict__ outb) {
    __shared__ float xs[C_][66];
    unsigned short* xbf = (unsigned short*)(outb + XBF_OFF);
    int* cnt = (int*)(outb + CNT_OFF);
    const int t = threadIdx.x;
    const int n0 = blockIdx.x * 64;
    const int b = n0 >> 10, p0 = n0 & 1023;
    for (int i = 0; i < 64; ++i) {
        int f = t + 256 * i; int c = f >> 6, nl = f & 63;
        xs[c][nl] = x[(b * C_ + c) * P_ + p0 + nl];
    }
    __syncthreads();
    if (t < 64) {
        double acc = 0.0;
        for (int c = 0; c < C_; ++c) { float v = xs[c][t]; float pq = v * v; acc += (double)pq; }
        outf[QOFF + n0 + t] = (float)acc;     // xsq, overwritten later by index
        cnt[n0 + t] = 0;
    }
    for (int i = 0; i < 64; ++i) {
        int f = t + 256 * i; int nl = f >> 8, c = f & 255;
        xbf[(n0 + nl) * C_ + c] = bfbits(xs[c][nl]);
    }
}

// ---------- prep_cb: cbsq (f32 squares, f64 sum, round once) + bf16 copy ----------
__global__ __launch_bounds__(256) void prep_cb(const float* __restrict__ cb,
                                               char* __restrict__ outb) {
    float* cbsq = (float*)(outb + CBSQ_OFF);
    unsigned short* cbbf = (unsigned short*)(outb + CBBF_OFF);
    const int row  = blockIdx.x * 4 + (threadIdx.x >> 6);
    const int lane = threadIdx.x & 63;
    const float4 v = *reinterpret_cast<const float4*>(cb + row * C_ + lane * 4);
    float p0 = v.x * v.x, p1 = v.y * v.y, p2 = v.z * v.z, p3 = v.w * v.w;
    double acc = (double)p0 + (double)p1 + (double)p2 + (double)p3;
    for (int off = 32; off; off >>= 1) acc += __shfl_down(acc, off, 64);
    if (lane == 0) cbsq[row] = (float)acc;
    ushort4 u = { bfbits(v.x), bfbits(v.y), bfbits(v.z), bfbits(v.w) };
    *reinterpret_cast<ushort4*>(cbbf + row * C_ + lane * 4) = u;
}

// ---------- vq_screen: XCD-affine chunk + wave-private pipeline ----------
// grid 1024: XCDs 0-3 own chunk0 (2MB, L2-resident), 4-7 chunk1. Block = 64 n,
// 4 waves x 1024-k quarters. Shared LDS running-min; LDS cand lists; flush once.
__global__ __launch_bounds__(256, 2) void vq_screen(char* __restrict__ outb) {
    __shared__ unsigned short Bt[4][8192];   // 16KB per wave (2 x 8KB dbuf)
    __shared__ unsigned lth[64];             // running row-min (fkey)
    __shared__ int cntL[64];
    __shared__ int candL[64 * CAPL];         // 11.5KB
    const unsigned short* xbf  = (const unsigned short*)(outb + XBF_OFF);
    const unsigned short* cbbf = (const unsigned short*)(outb + CBBF_OFF);
    const float* cbsq = (const float*)(outb + CBSQ_OFF);
    int* gcnt  = (int*)(outb + CNT_OFF);
    int* gcand = (int*)(outb + CAND_OFF);

    const int t = threadIdx.x;
    const int l = t & 63, w = t >> 6;
    const int id = blockIdx.x;
    const int xcd = id & 7;
    const int chunk0 = (xcd >> 2) * (K_ / 2);       // XCD 0-3 -> 0, 4-7 -> 4096
    const int n0 = ((id >> 3) * 4 + (xcd & 3)) * 64;  // bijective over 512 groups
    const int k0w = chunk0 + w * 1024;              // wave's quarter
    unsigned short* myB = &Bt[w][0];

    if (t < 64) { lth[t] = fkey(3.0e38f); cntL[t] = 0; }

    // --- wave-local x B-frags for the block's 64 rows (two 32-row stages) ---
    bf16x8 bx[4][8];
    #pragma unroll
    for (int half = 0; half < 2; ++half) {
        #pragma unroll
        for (int s = 0; s < 16; ++s) {
            const int dr = 2 * s + (l >> 5);
            gload_lds16(xbf + (size_t)(n0 + half * 32 + dr) * C_ + (((l & 31) ^ (dr & 7)) * 8),
                        (char*)myB + s * 1024);
        }
        asm volatile("s_waitcnt vmcnt(0)" ::: "memory");
        __builtin_amdgcn_sched_barrier(0);
        #pragma unroll
        for (int jj = 0; jj < 2; ++jj) {
            const int j = half * 2 + jj;
            const int r = jj * 16 + (l & 15);
            #pragma unroll
            for (int kc = 0; kc < 8; ++kc) {
                const int gs = (kc * 4 + (l >> 4)) ^ (r & 7);
                bx[j][kc] = *reinterpret_cast<const bf16x8*>((const char*)myB + r * 512 + gs * 16);
            }
        }
        asm volatile("s_waitcnt lgkmcnt(0)" ::: "memory");
        __builtin_amdgcn_sched_barrier(0);
    }
    __syncthreads();                         // lth/cntL init visible

    auto stageP = [&](int p, int half) {     // 16 k-rows = 8 gload_lds
        const unsigned short* src = cbbf + (size_t)(k0w + p * PANEL) * C_;
        #pragma unroll
        for (int s = 0; s < 8; ++s) {
            const int dr = 2 * s + (l >> 5);
            gload_lds16(src + (size_t)dr * C_ + (((l & 31) ^ (dr & 7)) * 8),
                        (char*)myB + half * 8192 + s * 1024);
        }
    };
    auto body = [&](int half, float4 cqv, int p) {
        f32x4 acc[4];
        #pragma unroll
        for (int j = 0; j < 4; ++j) acc[j] = (f32x4)(0.f);
        const int r = l & 15;
        #pragma unroll
        for (int kc = 0; kc < 8; ++kc) {
            const int gs = (kc * 4 + (l >> 4)) ^ (r & 7);
            const bf16x8 ak = *reinterpret_cast<const bf16x8*>(
                (const char*)myB + half * 8192 + r * 512 + gs * 16);
            #pragma unroll
            for (int j = 0; j < 4; ++j)
                acc[j] = __builtin_amdgcn_mfma_f32_16x16x32_bf16(ak, bx[j][kc], acc[j], 0, 0, 0);
        }
        const float cq[4] = {cqv.x, cqv.y, cqv.z, cqv.w};
        #pragma unroll
        for (int j = 0; j < 4; ++j) {
            #pragma unroll
            for (int q = 0; q < 4; ++q) acc[j][q] = fmaf(-2.f, acc[j][q], cq[q]);
            float m = fminf(fminf(acc[j][0], acc[j][1]), fminf(acc[j][2], acc[j][3]));
            m = fminf(m, __shfl_xor(m, 16, 64));
            m = fminf(m, __shfl_xor(m, 32, 64));
            if (l < 16) atomicMin(&lth[j * 16 + l], fkey(m));
        }
        #pragma unroll
        for (int j = 0; j < 4; ++j) {
            const int rloc = j * 16 + (l & 15);
            const float th = funkey(lth[rloc]) + EPS;
            #pragma unroll
            for (int q = 0; q < 4; ++q) {
                if (acc[j][q] < th) {
                    const int kg = k0w + p * PANEL + (l >> 4) * 4 + q;
                    const int pos = atomicAdd(&cntL[rloc], 1);
                    if (pos < CAPL) candL[rloc * CAPL + pos] = kg;
                }
            }
        }
    };
    auto csq = [&](int p) {
        return *reinterpret_cast<const float4*>(cbsq + k0w + p * PANEL + (l >> 4) * 4);
    };

    // --- wave-private pipeline: 9 VM loads/half-step, counted vmcnt, no barriers ---
    stageP(0, 0); float4 cqA = csq(0);
    stageP(1, 1); float4 cqB = csq(1);
    for (int pp = 0; pp < NPANELW; pp += 2) {
        asm volatile("s_waitcnt vmcnt(9)" ::: "memory");
        __builtin_amdgcn_sched_barrier(0);
        body(0, cqA, pp);
        asm volatile("s_waitcnt lgkmcnt(0)" ::: "memory");
        __builtin_amdgcn_sched_barrier(0);
        stageP((pp + 2) & (NPANELW - 1), 0); cqA = csq((pp + 2) & (NPANELW - 1));
        asm volatile("s_waitcnt vmcnt(9)" ::: "memory");
        __builtin_amdgcn_sched_barrier(0);
        body(1, cqB, pp + 1);
        asm volatile("s_waitcnt lgkmcnt(0)" ::: "memory");
        __builtin_amdgcn_sched_barrier(0);
        stageP((pp + 3) & (NPANELW - 1), 1); cqB = csq((pp + 3) & (NPANELW - 1));
    }
    __syncthreads();                         // collects visible; vm drained

    // --- flush LDS lists to global (reserve via device-scope atomicAdd) ---
    for (int r = 0; r < 16; ++r) {
        const int rloc = w * 16 + r;
        const int n = n0 + rloc;
        const int m = cntL[rloc];
        int off = 0;
        if (l == 0) off = atomicAdd(&gcnt[n], (m > CAPL) ? 1000000 : m);
        off = __shfl(off, 0, 64);
        if (m > CAPL) continue;              // overflow flagged -> full scan
        for (int i = l; i < m; i += 64) {
            const int dst = off + i;
            if (dst < GCAP) gcand[(size_t)n * GCAP + dst] = candL[rloc * CAPL + i];
        }
    }
}

// ---------- rescore: exact f32 chain over candidates; fallback full scan ----------
__global__ __launch_bounds__(256, 2) void rescore(const float* __restrict__ x,
                                                  const float* __restrict__ cb,
                                                  float* __restrict__ outf,
                                                  char* __restrict__ outb) {
    __shared__ float xs[64 * 257];           // xs[row*257 + c]
    __shared__ float xrow[4][C_];            // per-wave aligned row (fallback)
    const float* cbsq = (const float*)(outb + CBSQ_OFF);
    const int*   gcnt = (const int*)(outb + CNT_OFF);
    const int*   gcand= (const int*)(outb + CAND_OFF);
    const int t = threadIdx.x, l = t & 63, w = t >> 6;
    const int nb = blockIdx.x * 64;
    const int b = nb >> 10, p0 = nb & 1023;
    for (int i = 0; i < 64; ++i) {
        int f = t + 256 * i; int c = f >> 6, nl = f & 63;
        xs[nl * 257 + c] = x[(b * C_ + c) * P_ + p0 + nl];
    }
    __syncthreads();

    for (int r = 0; r < 16; ++r) {
        const int row = w * 16 + r;
        const int n = nb + row;
        const int m = gcnt[n];
        const float xq = outf[QOFF + n];     // xsq (overwritten below)
        float s2 = 3e38f; int bk = 0x7FFFFFFF;

        if (m >= 1 && m <= GCAP) {
            float xl[4];
            #pragma unroll
            for (int cc = 0; cc < 4; ++cc) xl[cc] = xs[row * 257 + cc * 64 + l];
            for (int base = 0; base < m; base += 4) {
                int ku[4]; float pt[4];
                #pragma unroll
                for (int u = 0; u < 4; ++u) {
                    int ci = base + u; if (ci > m - 1) ci = m - 1;
                    ku[u] = gcand[(size_t)n * GCAP + ci];
                    float part = 0.f;
                    #pragma unroll
                    for (int cc = 0; cc < 4; ++cc)
                        part = fmaf(xl[cc], cb[(size_t)ku[u] * C_ + cc * 64 + l], part);
                    pt[u] = part;
                }
                #pragma unroll
                for (int off = 32; off; off >>= 1) {
                    #pragma unroll
                    for (int u = 0; u < 4; ++u) pt[u] += __shfl_xor(pt[u], off, 64);
                }
                #pragma unroll
                for (int u = 0; u < 4; ++u) {
                    if (base + u < m) {
                        const float sck = (xq - 2.0f * pt[u]) + cbsq[ku[u]];
                        if (sck < s2 || (sck == s2 && ku[u] < bk)) { s2 = sck; bk = ku[u]; }
                    }
                }
            }
        } else {
            // overflow fallback (P ~ 0): lane-per-k exact scan
            #pragma unroll
            for (int i = 0; i < 4; ++i) xrow[w][l + 64 * i] = xs[row * 257 + l + 64 * i];
            asm volatile("s_waitcnt lgkmcnt(0)" ::: "memory");
            __builtin_amdgcn_sched_barrier(0);
            for (int kk = 0; kk < K_ / 64; ++kk) {
                const int k = 64 * kk + l;
                float acc = 0.f;
                #pragma unroll 8
                for (int c4 = 0; c4 < 64; ++c4) {
                    const float4 xv = *reinterpret_cast<const float4*>(&xrow[w][c4 * 4]);
                    const float4 cv = *reinterpret_cast<const float4*>(&cb[(size_t)k * C_ + c4 * 4]);
                    acc = fmaf(xv.x, cv.x, acc); acc = fmaf(xv.y, cv.y, acc);
                    acc = fmaf(xv.z, cv.z, acc); acc = fmaf(xv.w, cv.w, acc);
                }
                const float sck = (xq - 2.0f * acc) + cbsq[k];
                if (sck < s2 || (sck == s2 && k < bk)) { s2 = sck; bk = k; }
            }
        }
        #pragma unroll
        for (int off = 32; off; off >>= 1) {
            const float so = __shfl_xor(s2, off, 64);
            const int   ko = __shfl_xor(bk, off, 64);
            if (so < s2 || (so == s2 && ko < bk)) { s2 = so; bk = ko; }
        }
        if (l == 0) outf[QOFF + n] = (float)bk;
    }
}

// ---------- gather (separate, last): quantized[b][c][p] = cb[idx[n]][c] ----------
__global__ __launch_bounds__(256) void gather(const float* __restrict__ cb,
                                              float* __restrict__ outf) {
    __shared__ int kf[64];
    const int t = threadIdx.x;
    const int n0 = blockIdx.x * 64;
    const int b = n0 >> 10, p0 = n0 & 1023;
    if (t < 64) kf[t] = (int)outf[QOFF + n0 + t];
    __syncthreads();
    for (int i = 0; i < 64; ++i) {
        int f = t + 256 * i; int c = f >> 6, nl = f & 63;
        outf[(b * C_ + c) * P_ + p0 + nl] = cb[(size_t)kf[nl] * C_ + c];
    }
}

extern "C" void kernel_launch(void* const* d_in, const int* in_sizes, int n_in,
                              void* d_out, int out_size, void* d_ws, size_t ws_size,
                              hipStream_t stream) {
    const float* x  = (const float*)d_in[0];
    const float* cb = (const float*)d_in[1];
    float* outf = (float*)d_out;
    char*  outb = (char*)d_out;

    prep_x<<<N_ / 64, 256, 0, stream>>>(x, outf, outb);
    prep_cb<<<K_ / 4, 256, 0, stream>>>(cb, outb);
    vq_screen<<<1024, 256, 0, stream>>>(outb);
    rescore<<<N_ / 64, 256, 0, stream>>>(x, cb, outf, outb);
    gather<<<N_ / 64, 256, 0, stream>>>(cb, outf);
}